// Round 5
// baseline (129.427 us; speedup 1.0000x reference)
//
#include <hip/hip_runtime.h>

#define DDIM 128

// Stage A: stream x, compute per-sample ||x - a_y||^2.
// Each wave: one coalesced 64-label read per super-iter, then 8 register-blocked
// sub-iters of 8 samples (16-lane groups, 2 samples per group). Labels come from
// __shfl of the preloaded label vector, so anchor gathers issue without waiting
// on a fresh y load. Per-class sums/counts in LDS; per-block partial flush.
__global__ __launch_bounds__(256) void dist_kernel(
    const float* __restrict__ x, const float* __restrict__ anchors,
    const int* __restrict__ y,
    float* __restrict__ pseg, unsigned* __restrict__ pcnt,
    int n, int C)
{
    extern __shared__ char smem[];
    float*    segL = (float*)smem;
    unsigned* cntL = (unsigned*)(smem + (size_t)C * sizeof(float));

    for (int c = threadIdx.x; c < C; c += blockDim.x) { segL[c] = 0.0f; cntL[c] = 0u; }
    __syncthreads();

    const int tid  = blockIdx.x * blockDim.x + threadIdx.x;
    const int wave = tid >> 6;
    const int lane = threadIdx.x & 63;
    const int g    = lane >> 4;   // sample group within wave (0..3)
    const int q    = lane & 15;   // lane within 16-lane group
    const int totalWaves = (gridDim.x * blockDim.x) >> 6;
    const long long superStride = (long long)totalWaves * 64;  // 64 samples/wave/super-iter

    for (long long base = (long long)wave * 64; base < n; base += superStride) {
        // One coalesced label load for the wave's 64 samples.
        const long long yi = base + lane;
        int yv = (yi < n) ? y[yi] : 0;

        #pragma unroll 2
        for (int sub = 0; sub < 8; ++sub) {
            const long long i0 = base + sub * 8 + g;
            const long long i1 = i0 + 4;
            const bool v0 = i0 < n, v1 = i1 < n;

            const int l0 = __shfl(yv, sub * 8 + g);
            const int l1 = __shfl(yv, sub * 8 + g + 4);

            float4 xa0, xa1, xb0, xb1;
            float4 aa0, aa1, ab0, ab1;
            if (v0) {
                const float4* xp = (const float4*)(x + (size_t)i0 * DDIM + q * 8);
                const float4* ap = (const float4*)(anchors + (size_t)l0 * DDIM + q * 8);
                xa0 = xp[0]; xa1 = xp[1];
                aa0 = ap[0]; aa1 = ap[1];
            }
            if (v1) {
                const float4* xp = (const float4*)(x + (size_t)i1 * DDIM + q * 8);
                const float4* ap = (const float4*)(anchors + (size_t)l1 * DDIM + q * 8);
                xb0 = xp[0]; xb1 = xp[1];
                ab0 = ap[0]; ab1 = ap[1];
            }

            float acc0 = 0.0f, acc1 = 0.0f;
            if (v0) {
                float d;
                d = xa0.x - aa0.x; acc0 = fmaf(d, d, acc0);
                d = xa0.y - aa0.y; acc0 = fmaf(d, d, acc0);
                d = xa0.z - aa0.z; acc0 = fmaf(d, d, acc0);
                d = xa0.w - aa0.w; acc0 = fmaf(d, d, acc0);
                d = xa1.x - aa1.x; acc0 = fmaf(d, d, acc0);
                d = xa1.y - aa1.y; acc0 = fmaf(d, d, acc0);
                d = xa1.z - aa1.z; acc0 = fmaf(d, d, acc0);
                d = xa1.w - aa1.w; acc0 = fmaf(d, d, acc0);
            }
            if (v1) {
                float d;
                d = xb0.x - ab0.x; acc1 = fmaf(d, d, acc1);
                d = xb0.y - ab0.y; acc1 = fmaf(d, d, acc1);
                d = xb0.z - ab0.z; acc1 = fmaf(d, d, acc1);
                d = xb0.w - ab0.w; acc1 = fmaf(d, d, acc1);
                d = xb1.x - ab1.x; acc1 = fmaf(d, d, acc1);
                d = xb1.y - ab1.y; acc1 = fmaf(d, d, acc1);
                d = xb1.z - ab1.z; acc1 = fmaf(d, d, acc1);
                d = xb1.w - ab1.w; acc1 = fmaf(d, d, acc1);
            }

            #pragma unroll
            for (int off = 1; off < 16; off <<= 1) {
                acc0 += __shfl_xor(acc0, off);
                acc1 += __shfl_xor(acc1, off);
            }
            if (q == 0) {
                if (v0) { atomicAdd(&segL[l0], acc0); atomicAdd(&cntL[l0], 1u); }
                if (v1) { atomicAdd(&segL[l1], acc1); atomicAdd(&cntL[l1], 1u); }
            }
        }
    }
    __syncthreads();

    float*    myseg = pseg + (size_t)blockIdx.x * C;
    unsigned* mycnt = pcnt + (size_t)blockIdx.x * C;
    for (int c = threadIdx.x; c < C; c += blockDim.x) {
        myseg[c] = segL[c];
        mycnt[c] = cntL[c];
    }
}

// Stage B: 2-D grid (class-chunk, b-slice). Thread t owns class chunk*256+t and
// sums rowsPerSlice consecutive partial rows — coalesced reads across threads.
__global__ __launch_bounds__(256) void reduceB_kernel(
    const float* __restrict__ pseg, const unsigned* __restrict__ pcnt,
    float* __restrict__ sseg, float* __restrict__ scnt,
    int B, int C, int rowsPerSlice)
{
    const int c = blockIdx.x * 256 + threadIdx.x;
    if (c >= C) return;
    const int slice = blockIdx.y;
    const int b0 = slice * rowsPerSlice;
    int b1 = b0 + rowsPerSlice; if (b1 > B) b1 = B;

    float s = 0.0f, k = 0.0f;
    #pragma unroll 8
    for (int b = b0; b < b1; ++b) {
        s += pseg[(size_t)b * C + c];
        k += (float)pcnt[(size_t)b * C + c];
    }
    sseg[(size_t)slice * C + c] = s;
    scnt[(size_t)slice * C + c] = k;
}

// Stage C: one block; thread per class sums slice partials (coalesced),
// applies s/k^2, block-reduces to out[0].
__global__ __launch_bounds__(1024) void finalize_kernel(
    const float* __restrict__ sseg, const float* __restrict__ scnt,
    float* __restrict__ out, int nslice, int C)
{
    __shared__ float red[1024];
    const int t = threadIdx.x;
    float v = 0.0f;
    for (int c = t; c < C; c += 1024) {
        float s = 0.0f, k = 0.0f;
        for (int sl = 0; sl < nslice; ++sl) {
            s += sseg[(size_t)sl * C + c];
            k += scnt[(size_t)sl * C + c];
        }
        if (k > 0.0f) v += s / (k * k);
    }
    red[t] = v;
    __syncthreads();
    #pragma unroll
    for (int st = 512; st > 0; st >>= 1) {
        if (t < st) red[t] += red[t + st];
        __syncthreads();
    }
    if (t == 0) out[0] = red[0];
}

extern "C" void kernel_launch(void* const* d_in, const int* in_sizes, int n_in,
                              void* d_out, int out_size, void* d_ws, size_t ws_size,
                              hipStream_t stream) {
    const float* x       = (const float*)d_in[0];
    const float* anchors = (const float*)d_in[1];
    const int*   y       = (const int*)d_in[2];
    float*       out     = (float*)d_out;

    const int n = in_sizes[2];          // N samples
    const int C = in_sizes[1] / DDIM;   // classes

    const int rowsPerSlice = 64;

    // ws layout: pseg[B*C] f32 | pcnt[B*C] u32 | sseg[nslice*C] f32 | scnt[nslice*C] f32
    long long cap = ((long long)ws_size) / ((long long)C * 8 + (long long)C * 16 / rowsPerSlice + 16);
    int B = (int)(cap < 1 ? 1 : (cap > 2048 ? 2048 : cap));
    const int nslice = (B + rowsPerSlice - 1) / rowsPerSlice;

    float*    pseg = (float*)d_ws;
    unsigned* pcnt = (unsigned*)((char*)d_ws + (size_t)B * C * 4);
    float*    sseg = (float*)((char*)d_ws + (size_t)B * C * 8);
    float*    scnt = (float*)((char*)d_ws + (size_t)B * C * 8 + (size_t)nslice * C * 4);

    const size_t ldsBytes = (size_t)C * 8;  // segL + cntL
    dist_kernel<<<B, 256, ldsBytes, stream>>>(x, anchors, y, pseg, pcnt, n, C);

    dim3 gridB((C + 255) / 256, nslice);
    reduceB_kernel<<<gridB, 256, 0, stream>>>(pseg, pcnt, sseg, scnt, B, C, rowsPerSlice);

    finalize_kernel<<<1, 1024, 0, stream>>>(sseg, scnt, out, nslice, C);
}

// Round 6
// 124.270 us; speedup vs baseline: 1.0415x; 1.0415x over previous
//
#include <hip/hip_runtime.h>

#define DDIM 128

// Stage A: stream x, compute per-sample ||x - a_y||^2 via 16-lane groups
// (2 samples per group per iteration). Branch-free main loop over full
// 8-sample tiles (all 10 VMEM ops of an iteration issue unguarded,
// back-to-back); guarded tail handles the last partial tile. Per-class
// sums/counts in LDS; per-block partial flush (no global atomics).
__global__ __launch_bounds__(256) void dist_kernel(
    const float* __restrict__ x, const float* __restrict__ anchors,
    const int* __restrict__ y,
    float* __restrict__ pseg, unsigned* __restrict__ pcnt,
    int n, int C)
{
    extern __shared__ char smem[];
    float*    segL = (float*)smem;
    unsigned* cntL = (unsigned*)(smem + (size_t)C * sizeof(float));

    for (int c = threadIdx.x; c < C; c += blockDim.x) { segL[c] = 0.0f; cntL[c] = 0u; }
    __syncthreads();

    const int tid  = blockIdx.x * blockDim.x + threadIdx.x;
    const int wave = tid >> 6;
    const int lane = threadIdx.x & 63;
    const int g    = lane >> 4;   // sample group within wave (0..3)
    const int q    = lane & 15;   // lane within 16-lane group
    const int totalWaves = (gridDim.x * blockDim.x) >> 6;
    const int stride = totalWaves * 8;          // 8 samples per wave per iter

    int base = wave * 8;
    for (; base + 8 <= n; base += stride) {
        const int i0 = base + g;        // sample A for this group
        const int i1 = i0 + 4;          // sample B for this group

        const int l0 = y[i0];
        const int l1 = y[i1];

        // All offsets fit 32-bit: n*DDIM = 1.28e8 floats, C*DDIM = 1.28e5.
        const float4* xpa = (const float4*)(x + ((unsigned)i0 << 7) + (q << 3));
        const float4* xpb = (const float4*)(x + ((unsigned)i1 << 7) + (q << 3));
        const float4* apa = (const float4*)(anchors + ((unsigned)l0 << 7) + (q << 3));
        const float4* apb = (const float4*)(anchors + ((unsigned)l1 << 7) + (q << 3));

        float4 xa0 = xpa[0], xa1 = xpa[1];
        float4 xb0 = xpb[0], xb1 = xpb[1];
        float4 aa0 = apa[0], aa1 = apa[1];
        float4 ab0 = apb[0], ab1 = apb[1];

        float acc0 = 0.0f, acc1 = 0.0f;
        float d;
        d = xa0.x - aa0.x; acc0 = fmaf(d, d, acc0);
        d = xa0.y - aa0.y; acc0 = fmaf(d, d, acc0);
        d = xa0.z - aa0.z; acc0 = fmaf(d, d, acc0);
        d = xa0.w - aa0.w; acc0 = fmaf(d, d, acc0);
        d = xa1.x - aa1.x; acc0 = fmaf(d, d, acc0);
        d = xa1.y - aa1.y; acc0 = fmaf(d, d, acc0);
        d = xa1.z - aa1.z; acc0 = fmaf(d, d, acc0);
        d = xa1.w - aa1.w; acc0 = fmaf(d, d, acc0);
        d = xb0.x - ab0.x; acc1 = fmaf(d, d, acc1);
        d = xb0.y - ab0.y; acc1 = fmaf(d, d, acc1);
        d = xb0.z - ab0.z; acc1 = fmaf(d, d, acc1);
        d = xb0.w - ab0.w; acc1 = fmaf(d, d, acc1);
        d = xb1.x - ab1.x; acc1 = fmaf(d, d, acc1);
        d = xb1.y - ab1.y; acc1 = fmaf(d, d, acc1);
        d = xb1.z - ab1.z; acc1 = fmaf(d, d, acc1);
        d = xb1.w - ab1.w; acc1 = fmaf(d, d, acc1);

        #pragma unroll
        for (int off = 1; off < 16; off <<= 1) {
            acc0 += __shfl_xor(acc0, off);
            acc1 += __shfl_xor(acc1, off);
        }
        if (q == 0) {
            atomicAdd(&segL[l0], acc0); atomicAdd(&cntL[l0], 1u);
            atomicAdd(&segL[l1], acc1); atomicAdd(&cntL[l1], 1u);
        }
    }

    // Tail: at most one wave owns the straddling tile.
    if (base < n) {
        const int i0 = base + g;
        const int i1 = i0 + 4;
        const bool v0 = i0 < n, v1 = i1 < n;
        int l0 = 0, l1 = 0;
        if (v0) l0 = y[i0];
        if (v1) l1 = y[i1];

        float acc0 = 0.0f, acc1 = 0.0f;
        if (v0) {
            const float4* xp = (const float4*)(x + ((unsigned)i0 << 7) + (q << 3));
            const float4* ap = (const float4*)(anchors + ((unsigned)l0 << 7) + (q << 3));
            float4 x0 = xp[0], x1 = xp[1], a0 = ap[0], a1 = ap[1];
            float d;
            d = x0.x - a0.x; acc0 = fmaf(d, d, acc0);
            d = x0.y - a0.y; acc0 = fmaf(d, d, acc0);
            d = x0.z - a0.z; acc0 = fmaf(d, d, acc0);
            d = x0.w - a0.w; acc0 = fmaf(d, d, acc0);
            d = x1.x - a1.x; acc0 = fmaf(d, d, acc0);
            d = x1.y - a1.y; acc0 = fmaf(d, d, acc0);
            d = x1.z - a1.z; acc0 = fmaf(d, d, acc0);
            d = x1.w - a1.w; acc0 = fmaf(d, d, acc0);
        }
        if (v1) {
            const float4* xp = (const float4*)(x + ((unsigned)i1 << 7) + (q << 3));
            const float4* ap = (const float4*)(anchors + ((unsigned)l1 << 7) + (q << 3));
            float4 x0 = xp[0], x1 = xp[1], a0 = ap[0], a1 = ap[1];
            float d;
            d = x0.x - a0.x; acc1 = fmaf(d, d, acc1);
            d = x0.y - a0.y; acc1 = fmaf(d, d, acc1);
            d = x0.z - a0.z; acc1 = fmaf(d, d, acc1);
            d = x0.w - a0.w; acc1 = fmaf(d, d, acc1);
            d = x1.x - a1.x; acc1 = fmaf(d, d, acc1);
            d = x1.y - a1.y; acc1 = fmaf(d, d, acc1);
            d = x1.z - a1.z; acc1 = fmaf(d, d, acc1);
            d = x1.w - a1.w; acc1 = fmaf(d, d, acc1);
        }

        #pragma unroll
        for (int off = 1; off < 16; off <<= 1) {
            acc0 += __shfl_xor(acc0, off);
            acc1 += __shfl_xor(acc1, off);
        }
        if (q == 0) {
            if (v0) { atomicAdd(&segL[l0], acc0); atomicAdd(&cntL[l0], 1u); }
            if (v1) { atomicAdd(&segL[l1], acc1); atomicAdd(&cntL[l1], 1u); }
        }
    }
    __syncthreads();

    float*    myseg = pseg + (size_t)blockIdx.x * C;
    unsigned* mycnt = pcnt + (size_t)blockIdx.x * C;
    for (int c = threadIdx.x; c < C; c += blockDim.x) {
        myseg[c] = segL[c];
        mycnt[c] = cntL[c];
    }
}

// Stage B: 2-D grid (class-chunk, b-slice). Thread t owns class chunk*256+t and
// sums rowsPerSlice consecutive partial rows — coalesced reads across threads.
__global__ __launch_bounds__(256) void reduceB_kernel(
    const float* __restrict__ pseg, const unsigned* __restrict__ pcnt,
    float* __restrict__ sseg, float* __restrict__ scnt,
    int B, int C, int rowsPerSlice)
{
    const int c = blockIdx.x * 256 + threadIdx.x;
    if (c >= C) return;
    const int slice = blockIdx.y;
    const int b0 = slice * rowsPerSlice;
    int b1 = b0 + rowsPerSlice; if (b1 > B) b1 = B;

    float s = 0.0f, k = 0.0f;
    #pragma unroll 8
    for (int b = b0; b < b1; ++b) {
        s += pseg[(size_t)b * C + c];
        k += (float)pcnt[(size_t)b * C + c];
    }
    sseg[(size_t)slice * C + c] = s;
    scnt[(size_t)slice * C + c] = k;
}

// Stage C: one block; thread per class sums slice partials (coalesced),
// applies s/k^2, block-reduces to out[0].
__global__ __launch_bounds__(1024) void finalize_kernel(
    const float* __restrict__ sseg, const float* __restrict__ scnt,
    float* __restrict__ out, int nslice, int C)
{
    __shared__ float red[1024];
    const int t = threadIdx.x;
    float v = 0.0f;
    for (int c = t; c < C; c += 1024) {
        float s = 0.0f, k = 0.0f;
        for (int sl = 0; sl < nslice; ++sl) {
            s += sseg[(size_t)sl * C + c];
            k += scnt[(size_t)sl * C + c];
        }
        if (k > 0.0f) v += s / (k * k);
    }
    red[t] = v;
    __syncthreads();
    #pragma unroll
    for (int st = 512; st > 0; st >>= 1) {
        if (t < st) red[t] += red[t + st];
        __syncthreads();
    }
    if (t == 0) out[0] = red[0];
}

extern "C" void kernel_launch(void* const* d_in, const int* in_sizes, int n_in,
                              void* d_out, int out_size, void* d_ws, size_t ws_size,
                              hipStream_t stream) {
    const float* x       = (const float*)d_in[0];
    const float* anchors = (const float*)d_in[1];
    const int*   y       = (const int*)d_in[2];
    float*       out     = (float*)d_out;

    const int n = in_sizes[2];          // N samples
    const int C = in_sizes[1] / DDIM;   // classes

    const int rowsPerSlice = 64;

    // ws layout: pseg[B*C] f32 | pcnt[B*C] u32 | sseg[nslice*C] f32 | scnt[nslice*C] f32
    long long cap = ((long long)ws_size) / ((long long)C * 8 + (long long)C * 16 / rowsPerSlice + 16);
    int B = (int)(cap < 1 ? 1 : (cap > 2048 ? 2048 : cap));
    const int nslice = (B + rowsPerSlice - 1) / rowsPerSlice;

    float*    pseg = (float*)d_ws;
    unsigned* pcnt = (unsigned*)((char*)d_ws + (size_t)B * C * 4);
    float*    sseg = (float*)((char*)d_ws + (size_t)B * C * 8);
    float*    scnt = (float*)((char*)d_ws + (size_t)B * C * 8 + (size_t)nslice * C * 4);

    const size_t ldsBytes = (size_t)C * 8;  // segL + cntL
    dist_kernel<<<B, 256, ldsBytes, stream>>>(x, anchors, y, pseg, pcnt, n, C);

    dim3 gridB((C + 255) / 256, nslice);
    reduceB_kernel<<<gridB, 256, 0, stream>>>(pseg, pcnt, sseg, scnt, B, C, rowsPerSlice);

    finalize_kernel<<<1, 1024, 0, stream>>>(sseg, scnt, out, nslice, C);
}